// Round 1
// baseline (827.054 us; speedup 1.0000x reference)
//
#include <hip/hip_runtime.h>

#define NPTS 16384
#define KNN 16
#define HID 64
#define NCLS 10
#define CHUNKS 8
#define CHUNK (NPTS / CHUNKS)   // 2048
#define CAP 320                 // survivor cap per query

// distance helper: identical fmaf chain in every kernel so τ comparisons are
// bit-exact across passes (drop sq_i: rank-invariant per query)
__device__ __forceinline__ float distf(float4 q, float4 p) {
    float dot = fmaf(q.x, p.x, fmaf(q.y, p.y, q.z * p.z));
    return fmaf(-2.f, dot, p.w);
}

// pos (N,3) -> pos4 (x,y,z,|p|^2)
__global__ void prep_kernel(const float* __restrict__ pos, float4* __restrict__ pos4) {
    int i = blockIdx.x * 256 + threadIdx.x;
    if (i < NPTS) {
        float x = pos[3 * i], y = pos[3 * i + 1], z = pos[3 * i + 2];
        pos4[i] = make_float4(x, y, z, fmaf(x, x, fmaf(y, y, z * z)));
    }
}

// Pass 1: per (query, chunk): 16 stream-minima (stream = global j mod 16). Branchless.
__global__ __launch_bounds__(256) void knn_tau_kernel(const float4* __restrict__ pos4,
                                                      float* __restrict__ minpart) {
    int q = blockIdx.x * 256 + threadIdx.x;
    int c = blockIdx.y;
    float4 qp = pos4[q];
    float mn[16];
#pragma unroll
    for (int u = 0; u < 16; ++u) mn[u] = INFINITY;
    __shared__ float4 tile[256];
    int base = c * CHUNK;
    for (int t0 = 0; t0 < CHUNK; t0 += 256) {
        __syncthreads();
        tile[threadIdx.x] = pos4[base + t0 + threadIdx.x];
        __syncthreads();
        for (int jj = 0; jj < 256; jj += 16) {
#pragma unroll
            for (int u = 0; u < 16; ++u) {
                float d = distf(qp, tile[jj + u]);
                mn[u] = fminf(mn[u], d);
            }
        }
    }
#pragma unroll
    for (int u = 0; u < 16; ++u) minpart[(q * CHUNKS + c) * 16 + u] = mn[u];
}

// tau[q] = max over 16 streams of (min over chunks). Guaranteed >= d_16(q).
__global__ void knn_tau_reduce_kernel(const float* __restrict__ minpart, float* __restrict__ tau) {
    int q = blockIdx.x * 256 + threadIdx.x;
    float t = -INFINITY;
#pragma unroll
    for (int u = 0; u < 16; ++u) {
        float m = INFINITY;
#pragma unroll
        for (int c = 0; c < CHUNKS; ++c) m = fminf(m, minpart[(q * CHUNKS + c) * 16 + u]);
        t = fmaxf(t, m);
    }
    tau[q] = t;
}

// Pass 2: collect survivors d <= tau into per-query buffer
__global__ __launch_bounds__(256) void knn_collect_kernel(const float4* __restrict__ pos4,
                                                          const float* __restrict__ tau,
                                                          int* __restrict__ surv,
                                                          int* __restrict__ cnt,
                                                          int* __restrict__ flags) {
    int q = blockIdx.x * 256 + threadIdx.x;
    int c = blockIdx.y;
    float4 qp = pos4[q];
    float tq = tau[q];
    __shared__ float4 tile[256];
    int base = c * CHUNK;
    for (int t0 = 0; t0 < CHUNK; t0 += 256) {
        __syncthreads();
        tile[threadIdx.x] = pos4[base + t0 + threadIdx.x];
        __syncthreads();
#pragma unroll 8
        for (int jj = 0; jj < 256; ++jj) {
            float d = distf(qp, tile[jj]);
            if (d <= tq) {
                int p = atomicAdd(&cnt[q], 1);
                if (p < CAP) surv[q * CAP + p] = base + t0 + jj;
                else flags[q] = 1;
            }
        }
    }
}

__device__ __forceinline__ void insert16(float v, int vi, float d[16], int id[16]) {
    // tie-break on lower index to match lax.top_k
    if (v < d[15] || (v == d[15] && vi < id[15])) {
        float cv = v; int ci = vi;
#pragma unroll
        for (int s = 0; s < 16; ++s) {
            bool sw = (cv < d[s]) || (cv == d[s] && ci < id[s]);
            float td = d[s]; int ti = id[s];
            if (sw) { d[s] = cv; id[s] = ci; cv = td; ci = ti; }
        }
    }
}

// Pass 3: exact top-16 from survivors
__global__ void knn_select_kernel(const float4* __restrict__ pos4, const int* __restrict__ surv,
                                  const int* __restrict__ cnt, int* __restrict__ idx) {
    int q = blockIdx.x * 256 + threadIdx.x;
    int n = min(cnt[q], CAP);
    float4 qp = pos4[q];
    float d[16]; int id[16];
#pragma unroll
    for (int u = 0; u < 16; ++u) { d[u] = INFINITY; id[u] = 0x7fffffff; }
    for (int t = 0; t < n; ++t) {
        int j = surv[q * CAP + t];
        float v = distf(qp, pos4[j]);
        insert16(v, j, d, id);
    }
#pragma unroll
    for (int u = 0; u < 16; ++u) idx[q * KNN + u] = id[u];
}

// Safety net: full rescan for overflowed queries (expected: never taken)
__global__ void knn_fixup_kernel(const float4* __restrict__ pos4, const int* __restrict__ flags,
                                 int* __restrict__ idx) {
    int q = blockIdx.x * 256 + threadIdx.x;
    if (!flags[q]) return;
    float4 qp = pos4[q];
    float d[16]; int id[16];
#pragma unroll
    for (int u = 0; u < 16; ++u) { d[u] = INFINITY; id[u] = 0x7fffffff; }
    for (int j = 0; j < NPTS; ++j) {
        float v = distf(qp, pos4[j]);
        insert16(v, j, d, id);
    }
#pragma unroll
    for (int u = 0; u < 16; ++u) idx[q * KNN + u] = id[u];
}

// EdgeConv1: pos (F=3) -> h1 (64). m[t] = b1 + sum_f xi_f*(W1[f][t]-W1[3+f][t]) + sum_f xj_f*W1[3+f][t]
__global__ __launch_bounds__(256) void ec1_kernel(const float4* __restrict__ pos4,
                                                  const int* __restrict__ idx,
                                                  const float* __restrict__ W1,
                                                  const float* __restrict__ b1,
                                                  float* __restrict__ h1) {
    int t = threadIdx.x & 63;
    int p = blockIdx.x * 4 + (threadIdx.x >> 6);
    float4 xi = pos4[p];
    float w0 = W1[0 * HID + t], w1 = W1[1 * HID + t], w2 = W1[2 * HID + t];
    float v0 = W1[3 * HID + t], v1 = W1[4 * HID + t], v2 = W1[5 * HID + t];
    float C = b1[t] + xi.x * (w0 - v0) + xi.y * (w1 - v1) + xi.z * (w2 - v2);
    float m = -INFINITY;
#pragma unroll
    for (int k = 0; k < KNN; ++k) {
        int j = idx[p * KNN + k];
        float4 xj = pos4[j];
        float a = C + xj.x * v0 + xj.y * v1 + xj.z * v2;
        m = fmaxf(m, a);
    }
    h1[p * HID + t] = fmaxf(m, 0.f);
}

// EdgeConv2 fused with per-block partial max-pool.
// m[k][t] = C_t + sum_f h1_j[f] * W2[64+f][t],  C_t = b2[t] + sum_f h1_i[f]*(W2[f][t]-W2[64+f][t])
__global__ __launch_bounds__(256) void ec2_kernel(const float* __restrict__ h1,
                                                  const int* __restrict__ idx,
                                                  const float* __restrict__ W2,
                                                  const float* __restrict__ b2,
                                                  float* __restrict__ gpartial) {
    int t = threadIdx.x & 63;
    int lp = threadIdx.x >> 6;
    int p = blockIdx.x * 4 + lp;
    float wb[64];
#pragma unroll
    for (int f = 0; f < 64; ++f) wb[f] = W2[(64 + f) * HID + t];
    float C = b2[t];
    const float4* h14 = (const float4*)h1;
#pragma unroll
    for (int f4 = 0; f4 < 16; ++f4) {
        float4 hv = h14[p * 16 + f4];
        C += hv.x * (W2[(f4 * 4 + 0) * HID + t] - wb[f4 * 4 + 0]);
        C += hv.y * (W2[(f4 * 4 + 1) * HID + t] - wb[f4 * 4 + 1]);
        C += hv.z * (W2[(f4 * 4 + 2) * HID + t] - wb[f4 * 4 + 2]);
        C += hv.w * (W2[(f4 * 4 + 3) * HID + t] - wb[f4 * 4 + 3]);
    }
    float m = -INFINITY;
    for (int k = 0; k < KNN; ++k) {
        int j = idx[p * KNN + k];
        float acc = C;
#pragma unroll
        for (int f4 = 0; f4 < 16; ++f4) {
            float4 hv = h14[j * 16 + f4];
            acc = fmaf(hv.x, wb[f4 * 4 + 0], acc);
            acc = fmaf(hv.y, wb[f4 * 4 + 1], acc);
            acc = fmaf(hv.z, wb[f4 * 4 + 2], acc);
            acc = fmaf(hv.w, wb[f4 * 4 + 3], acc);
        }
        m = fmaxf(m, acc);
    }
    m = fmaxf(m, 0.f);
    __shared__ float red[4][64];
    red[lp][t] = m;
    __syncthreads();
    if (lp == 0) {
        float g = fmaxf(fmaxf(red[0][t], red[1][t]), fmaxf(red[2][t], red[3][t]));
        gpartial[blockIdx.x * 64 + t] = g;
    }
}

__global__ void greduce_kernel(const float* __restrict__ gpartial, float* __restrict__ g, int nb) {
    int f = blockIdx.x;
    float m = -INFINITY;
    for (int i = threadIdx.x; i < nb; i += 256) m = fmaxf(m, gpartial[i * 64 + f]);
    __shared__ float s[256];
    s[threadIdx.x] = m;
    __syncthreads();
    for (int st = 128; st > 0; st >>= 1) {
        if (threadIdx.x < st) s[threadIdx.x] = fmaxf(s[threadIdx.x], s[threadIdx.x + st]);
        __syncthreads();
    }
    if (threadIdx.x == 0) g[f] = s[0];
}

__global__ void head_kernel(const float* __restrict__ g, const float* __restrict__ Wc,
                            const float* __restrict__ bc, float* __restrict__ out) {
    int c = threadIdx.x;
    if (c < NCLS) {
        float a = bc[c];
#pragma unroll
        for (int h = 0; h < HID; ++h) a = fmaf(g[h], Wc[h * NCLS + c], a);
        out[c] = a;
    }
}

extern "C" void kernel_launch(void* const* d_in, const int* in_sizes, int n_in,
                              void* d_out, int out_size, void* d_ws, size_t ws_size,
                              hipStream_t stream) {
    const float* pos = (const float*)d_in[0];
    // d_in[1] = batch (all zeros, num_segments=1) -> unused
    const float* W1 = (const float*)d_in[2];
    const float* b1 = (const float*)d_in[3];
    const float* W2 = (const float*)d_in[4];
    const float* b2 = (const float*)d_in[5];
    const float* Wc = (const float*)d_in[6];
    const float* bc = (const float*)d_in[7];
    float* out = (float*)d_out;

    char* ws = (char*)d_ws;
    size_t o = 0;
    auto alloc = [&](size_t bytes) { size_t r = o; o += (bytes + 255) & ~size_t(255); return r; };
    size_t o_pos4 = alloc((size_t)NPTS * 16);
    size_t o_tau = alloc((size_t)NPTS * 4);
    size_t o_minp = alloc((size_t)NPTS * CHUNKS * 16 * 4);
    size_t o_surv = alloc((size_t)NPTS * CAP * 4);
    size_t o_cnt = alloc((size_t)NPTS * 4);
    size_t o_flag = alloc((size_t)NPTS * 4);
    size_t o_idx = alloc((size_t)NPTS * KNN * 4);
    size_t o_h1 = alloc((size_t)NPTS * HID * 4);
    size_t o_gp = alloc((size_t)(NPTS / 4) * HID * 4);
    size_t o_g = alloc(256);

    float4* pos4 = (float4*)(ws + o_pos4);
    float* tau = (float*)(ws + o_tau);
    float* minp = (float*)(ws + o_minp);
    int* surv = (int*)(ws + o_surv);
    int* cnt = (int*)(ws + o_cnt);
    int* flags = (int*)(ws + o_flag);
    int* idx = (int*)(ws + o_idx);
    float* h1 = (float*)(ws + o_h1);
    float* gp = (float*)(ws + o_gp);
    float* g = (float*)(ws + o_g);

    hipMemsetAsync(ws + o_cnt, 0, (size_t)NPTS * 8, stream);  // cnt + flags (contiguous)

    prep_kernel<<<NPTS / 256, 256, 0, stream>>>(pos, pos4);
    knn_tau_kernel<<<dim3(NPTS / 256, CHUNKS), 256, 0, stream>>>(pos4, minp);
    knn_tau_reduce_kernel<<<NPTS / 256, 256, 0, stream>>>(minp, tau);
    knn_collect_kernel<<<dim3(NPTS / 256, CHUNKS), 256, 0, stream>>>(pos4, tau, surv, cnt, flags);
    knn_select_kernel<<<NPTS / 256, 256, 0, stream>>>(pos4, surv, cnt, idx);
    knn_fixup_kernel<<<NPTS / 256, 256, 0, stream>>>(pos4, flags, idx);
    ec1_kernel<<<NPTS / 4, 256, 0, stream>>>(pos4, idx, W1, b1, h1);
    ec2_kernel<<<NPTS / 4, 256, 0, stream>>>(h1, idx, W2, b2, gp);
    greduce_kernel<<<HID, 256, 0, stream>>>(gp, g, NPTS / 4);
    head_kernel<<<1, 64, 0, stream>>>(g, Wc, bc, out);
}